// Round 1
// baseline (994.245 us; speedup 1.0000x reference)
//
#include <hip/hip_runtime.h>
#include <hip/hip_bf16.h>

// Problem constants (GatedDeltaNet: B=2, T=1024, D=2048, HK=8, HV=16, DK=DV=128, KW=4)
#define B_ 2
#define T_ 1024
#define D_ 2048
#define HK_ 8
#define HV_ 16
#define DK_ 128
#define DV_ 128
#define KEY_DIM_ 1024
#define VALUE_DIM_ 2048
#define CONV_DIM_ 4096
#define BT_ 2048   // B*T

typedef __attribute__((ext_vector_type(8))) short short8;
typedef __attribute__((ext_vector_type(4))) float f32x4;

__device__ __forceinline__ short f2bf(float x) {
  __hip_bfloat16 h = __float2bfloat16(x);
  return *reinterpret_cast<short*>(&h);
}

// ---------------- cast f32 -> bf16 (vectorized) ----------------
__global__ void cast_plain(const float* __restrict__ in, short* __restrict__ out, int n4) {
  int i = blockIdx.x * blockDim.x + threadIdx.x;
  if (i < n4) {
    float4 v = ((const float4*)in)[i];
    short4 o;
    o.x = f2bf(v.x); o.y = f2bf(v.y); o.z = f2bf(v.z); o.w = f2bf(v.w);
    ((short4*)out)[i] = o;
  }
}

// ---------------- transpose + cast: W[R,C] f32 -> WT[C,R] bf16 ----------------
__global__ void transpose_cast(const float* __restrict__ W, short* __restrict__ WT, int R, int C) {
  __shared__ float tile[32][33];
  int tx = threadIdx.x, ty = threadIdx.y;
  int x = blockIdx.x * 32 + tx;
#pragma unroll
  for (int j = 0; j < 4; ++j) {
    int r = blockIdx.y * 32 + ty + j * 8;
    tile[ty + j * 8][tx] = W[(long)r * C + x];
  }
  __syncthreads();
  int ro = blockIdx.y * 32 + tx;
#pragma unroll
  for (int j = 0; j < 4; ++j) {
    int co = blockIdx.x * 32 + ty + j * 8;
    WT[(long)co * R + ro] = f2bf(tile[tx][ty + j * 8]);
  }
}

// ---------------- bf16 MFMA GEMM: C[M,N] f32 = A[M,K] * Bt[N,K]^T ----------------
// 128x128 tile, BK=32, 4 waves each computing a 64x64 quadrant via 4x4 MFMA 16x16x32.
__global__ __launch_bounds__(256) void gemm128(const short* __restrict__ A,
                                               const short* __restrict__ Bt,
                                               float* __restrict__ C,
                                               int M, int N, int K) {
  __shared__ short As[128][40];  // +8 pad: frag b128 reads land 2-way (free)
  __shared__ short Bs[128][40];
  int m0 = blockIdx.y * 128, n0 = blockIdx.x * 128;
  int tid = threadIdx.x;
  int wave = tid >> 6, lane = tid & 63;
  int wm = (wave >> 1) * 64, wn = (wave & 1) * 64;
  int quad = lane >> 4, l16 = lane & 15;
  f32x4 acc[4][4] = {};

  int ar = tid >> 2;            // 0..63
  int ac = (tid & 3) * 8;       // 0,8,16,24
  const short* Ap0 = A + (long)(m0 + ar) * K + ac;
  const short* Ap1 = A + (long)(m0 + 64 + ar) * K + ac;
  const short* Bp0 = Bt + (long)(n0 + ar) * K + ac;
  const short* Bp1 = Bt + (long)(n0 + 64 + ar) * K + ac;

  for (int k0 = 0; k0 < K; k0 += 32) {
    short8 a0 = *(const short8*)(Ap0 + k0);
    short8 a1 = *(const short8*)(Ap1 + k0);
    short8 b0 = *(const short8*)(Bp0 + k0);
    short8 b1 = *(const short8*)(Bp1 + k0);
    __syncthreads();
    *(short8*)(&As[ar][ac]) = a0;
    *(short8*)(&As[64 + ar][ac]) = a1;
    *(short8*)(&Bs[ar][ac]) = b0;
    *(short8*)(&Bs[64 + ar][ac]) = b1;
    __syncthreads();

    short8 af[4], bf_[4];
#pragma unroll
    for (int i = 0; i < 4; ++i) af[i] = *(const short8*)(&As[wm + i * 16 + l16][quad * 8]);
#pragma unroll
    for (int j = 0; j < 4; ++j) bf_[j] = *(const short8*)(&Bs[wn + j * 16 + l16][quad * 8]);
#pragma unroll
    for (int i = 0; i < 4; ++i)
#pragma unroll
      for (int j = 0; j < 4; ++j)
        acc[i][j] = __builtin_amdgcn_mfma_f32_16x16x32_bf16(af[i], bf_[j], acc[i][j], 0, 0, 0);
  }

#pragma unroll
  for (int i = 0; i < 4; ++i)
#pragma unroll
    for (int j = 0; j < 4; ++j)
#pragma unroll
      for (int r = 0; r < 4; ++r) {
        int row = m0 + wm + i * 16 + quad * 4 + r;
        int colx = n0 + wn + j * 16 + l16;
        C[(long)row * N + colx] = acc[i][j][r];
      }
}

// ---------------- beta / g projections (fp32 for precision) ----------------
__global__ __launch_bounds__(256) void small_proj(const float* __restrict__ hidden,
                                                  const float* __restrict__ Wb,
                                                  const float* __restrict__ Wa,
                                                  const float* __restrict__ dt_bias,
                                                  const float* __restrict__ A_log,
                                                  float* __restrict__ beta,
                                                  float* __restrict__ g) {
  __shared__ float red[256];
  int r = blockIdx.x;                     // row in [0, B*T)
  int tid = threadIdx.x;
  int h = tid & 31;                       // 0..15 -> W_b col, 16..31 -> W_a col
  int s = tid >> 5;                       // 0..7 K-slice
  const float* W = (h < 16) ? (Wb + h) : (Wa + (h - 16));
  const float* hp = hidden + (long)r * D_ + s * 256;
  float acc = 0.f;
#pragma unroll 8
  for (int i = 0; i < 256; ++i) acc += hp[i] * W[(s * 256 + i) * 16];
  red[tid] = acc;
  __syncthreads();
  if (tid < 32) {
    float t = 0.f;
#pragma unroll
    for (int ss = 0; ss < 8; ++ss) t += red[ss * 32 + tid];
    if (tid < 16) {
      beta[r * 16 + tid] = 1.f / (1.f + __expf(-t));
    } else {
      int hh = tid - 16;
      float y = t + dt_bias[hh];
      float sp = fmaxf(y, 0.f) + log1pf(__expf(-fabsf(y)));  // stable softplus
      g[r * 16 + hh] = -__expf(A_log[hh]) * sp;
    }
  }
}

// ---------------- depthwise causal conv (K=4) + SiLU ----------------
__global__ void conv_silu(const float* __restrict__ x, const float* __restrict__ w,
                          float* __restrict__ y) {
  int idx = blockIdx.x * 256 + threadIdx.x;     // B*T*CONV_DIM
  int c = idx & (CONV_DIM_ - 1);
  int bt = idx >> 12;
  int t = bt & (T_ - 1);
  float4 wc = *(const float4*)(w + c * 4);
  const float* xp = x + (long)idx;
  float acc = wc.w * xp[0];
  if (t >= 1) acc += wc.z * xp[-CONV_DIM_];
  if (t >= 2) acc += wc.y * xp[-2 * CONV_DIM_];
  if (t >= 3) acc += wc.x * xp[-3 * CONV_DIM_];
  y[idx] = acc * (1.f / (1.f + __expf(-acc)));
}

// ---------------- q/k l2norm (+ q scale) ----------------
__global__ __launch_bounds__(64) void qknorm(const float* __restrict__ qkv,
                                             float* __restrict__ qn, float* __restrict__ kn) {
  int bi = blockIdx.x;          // B*T*HK*2
  int which = bi & 1;           // 0=q, 1=k
  int h = (bi >> 1) & 7;
  int bt = bi >> 4;
  int lane = threadIdx.x;
  const float* src = qkv + (long)bt * CONV_DIM_ + which * KEY_DIM_ + h * DK_;
  float2 v = *(const float2*)(src + lane * 2);
  float ss = v.x * v.x + v.y * v.y;
#pragma unroll
  for (int m = 32; m; m >>= 1) ss += __shfl_xor(ss, m, 64);
  float scale = rsqrtf(ss + 1e-6f);
  if (which == 0) scale *= 0.08838834764831845f;  // DK^-0.5
  float* dst = (which ? kn : qn) + ((long)bt * HK_ + h) * DK_;
  float2 o; o.x = v.x * scale; o.y = v.y * scale;
  ((float2*)dst)[lane] = o;
}

// ---------------- gated delta-rule scan ----------------
// grid: 256 blocks = (b, hv, oct) ; block: 256 threads = 16 cols x 16 k-groups.
// Each thread holds 8 state rows (k = kt*8..kt*8+7) of one v-column in VGPRs.
__global__ __launch_bounds__(256) void scan_kernel(const float* __restrict__ qn,
                                                   const float* __restrict__ kn,
                                                   const float* __restrict__ qkv,
                                                   const float* __restrict__ gbuf,
                                                   const float* __restrict__ bbuf,
                                                   float* __restrict__ obuf) {
  int bi = blockIdx.x;
  int oct = bi & 7, hv = (bi >> 3) & 15, b = bi >> 7;
  int hk = hv >> 1;  // GQA repeat_interleave: expanded head j -> source j/2
  int tid = threadIdx.x;
  int kt = tid & 15, vg = tid >> 4;
  int col = oct * 16 + vg;

  const float* kp = kn + ((long)(b * T_) * HK_ + hk) * DK_ + kt * 8;
  const float* qp = qn + ((long)(b * T_) * HK_ + hk) * DK_ + kt * 8;
  const float* vp = qkv + (long)(b * T_) * CONV_DIM_ + 2 * KEY_DIM_ + hv * DV_ + col;
  const float* gp = gbuf + b * T_ * HV_ + hv;
  const float* bp = bbuf + b * T_ * HV_ + hv;
  float* op = obuf + ((long)(b * T_) * HV_ + hv) * DV_ + col;

  float S[8] = {0, 0, 0, 0, 0, 0, 0, 0};
  const int kstep = HK_ * DK_;    // 1024 floats per t
  const int vstep = CONV_DIM_;    // 4096

  float4 ka = *(const float4*)kp, kb = *(const float4*)(kp + 4);
  float4 qa = *(const float4*)qp, qb = *(const float4*)(qp + 4);
  float vv = *vp, gg = *gp, bb = *bp;

  for (int t = 0; t < T_; ++t) {
    int tn = (t < T_ - 1) ? t + 1 : t;   // prefetch next step (clamped)
    float4 nka = *(const float4*)(kp + (long)tn * kstep);
    float4 nkb = *(const float4*)(kp + (long)tn * kstep + 4);
    float4 nqa = *(const float4*)(qp + (long)tn * kstep);
    float4 nqb = *(const float4*)(qp + (long)tn * kstep + 4);
    float nvv = vp[(long)tn * vstep];
    float ngg = gp[tn * HV_];
    float nbb = bp[tn * HV_];

    float eg = __expf(gg);
    // kS partial on old S (decay folded: k . (S*eg) = eg * (k . S))
    float p0 = ka.x * S[0] + ka.y * S[1] + ka.z * S[2] + ka.w * S[3];
    float p1 = kb.x * S[4] + kb.y * S[5] + kb.z * S[6] + kb.w * S[7];
    float p = p0 + p1;
    p += __shfl_xor(p, 1, 16);
    p += __shfl_xor(p, 2, 16);
    p += __shfl_xor(p, 4, 16);
    p += __shfl_xor(p, 8, 16);
    float vadj = (vv - eg * p) * bb;
    S[0] = S[0] * eg + ka.x * vadj;
    S[1] = S[1] * eg + ka.y * vadj;
    S[2] = S[2] * eg + ka.z * vadj;
    S[3] = S[3] * eg + ka.w * vadj;
    S[4] = S[4] * eg + kb.x * vadj;
    S[5] = S[5] * eg + kb.y * vadj;
    S[6] = S[6] * eg + kb.z * vadj;
    S[7] = S[7] * eg + kb.w * vadj;
    float o0 = qa.x * S[0] + qa.y * S[1] + qa.z * S[2] + qa.w * S[3];
    float o1 = qb.x * S[4] + qb.y * S[5] + qb.z * S[6] + qb.w * S[7];
    float o = o0 + o1;      // off the recurrence critical path
    o += __shfl_xor(o, 1, 16);
    o += __shfl_xor(o, 2, 16);
    o += __shfl_xor(o, 4, 16);
    o += __shfl_xor(o, 8, 16);
    if (kt == 0) op[(long)t * VALUE_DIM_] = o;

    ka = nka; kb = nkb; qa = nqa; qb = nqb; vv = nvv; gg = ngg; bb = nbb;
  }
}

// ---------------- gated RMSNorm * silu(z), cast to bf16 ----------------
__global__ __launch_bounds__(64) void rms_gate(const float* __restrict__ obuf,
                                               const float* __restrict__ zbuf,
                                               const float* __restrict__ nw,
                                               short* __restrict__ obf) {
  int bi = blockIdx.x;          // B*T*HV
  int hv = bi & 15;
  int bt = bi >> 4;
  int lane = threadIdx.x;
  const float* o = obuf + ((long)bt * HV_ + hv) * DV_;
  float2 ov = *(const float2*)(o + lane * 2);
  float ss = ov.x * ov.x + ov.y * ov.y;
#pragma unroll
  for (int m = 32; m; m >>= 1) ss += __shfl_xor(ss, m, 64);
  float scale = rsqrtf(ss * (1.f / 128.f) + 1e-6f);
  float2 wv = *(const float2*)(nw + lane * 2);
  const float* z = zbuf + (long)bt * VALUE_DIM_ + hv * DV_;
  float2 zv = *(const float2*)(z + lane * 2);
  float s0 = zv.x * (1.f / (1.f + __expf(-zv.x)));
  float s1 = zv.y * (1.f / (1.f + __expf(-zv.y)));
  short2 r;
  r.x = f2bf(ov.x * scale * wv.x * s0);
  r.y = f2bf(ov.y * scale * wv.y * s1);
  ((short2*)(obf + ((long)bt * VALUE_DIM_ + hv * DV_)))[lane] = r;
}

// ---------------- launcher ----------------
extern "C" void kernel_launch(void* const* d_in, const int* in_sizes, int n_in,
                              void* d_out, int out_size, void* d_ws, size_t ws_size,
                              hipStream_t stream) {
  const float* hidden  = (const float*)d_in[0];
  const float* W_qkv   = (const float*)d_in[1];
  const float* W_z     = (const float*)d_in[2];
  const float* W_b     = (const float*)d_in[3];
  const float* W_a     = (const float*)d_in[4];
  const float* conv_w  = (const float*)d_in[5];
  const float* dt_bias = (const float*)d_in[6];
  const float* A_log   = (const float*)d_in[7];
  const float* norm_w  = (const float*)d_in[8];
  const float* W_out   = (const float*)d_in[9];
  float* out = (float*)d_out;

  char* ws = (char*)d_ws;
  size_t off = 0;
  auto alloc = [&](size_t bytes) {
    void* p = ws + off;
    off += (bytes + 255) & ~(size_t)255;
    return p;
  };
  short* hidden_bf = (short*)alloc((size_t)BT_ * D_ * 2);          // 8 MB
  short* WqkvT     = (short*)alloc((size_t)CONV_DIM_ * D_ * 2);    // 16 MB
  short* WzT       = (short*)alloc((size_t)VALUE_DIM_ * D_ * 2);   // 8 MB
  short* WoutT     = (short*)alloc((size_t)D_ * VALUE_DIM_ * 2);   // 8 MB
  float* mixed     = (float*)alloc((size_t)BT_ * CONV_DIM_ * 4);   // 32 MB
  float* qkv       = (float*)alloc((size_t)BT_ * CONV_DIM_ * 4);   // 32 MB
  float* zbuf      = (float*)alloc((size_t)BT_ * VALUE_DIM_ * 4);  // 16 MB
  float* qn        = (float*)alloc((size_t)BT_ * KEY_DIM_ * 4);    // 8 MB
  float* kn        = (float*)alloc((size_t)BT_ * KEY_DIM_ * 4);    // 8 MB
  float* betab     = (float*)alloc((size_t)BT_ * HV_ * 4);
  float* gb        = (float*)alloc((size_t)BT_ * HV_ * 4);
  float* obuf = mixed;       // alias: mixed dead after conv_silu
  short* obf  = hidden_bf;   // alias: hidden_bf dead after gemm(z)

  dim3 tb32(32, 8);
  cast_plain<<<(BT_ * D_ / 4 + 255) / 256, 256, 0, stream>>>(hidden, hidden_bf, BT_ * D_ / 4);
  transpose_cast<<<dim3(CONV_DIM_ / 32, D_ / 32), tb32, 0, stream>>>(W_qkv, WqkvT, D_, CONV_DIM_);
  transpose_cast<<<dim3(VALUE_DIM_ / 32, D_ / 32), tb32, 0, stream>>>(W_z, WzT, D_, VALUE_DIM_);
  transpose_cast<<<dim3(D_ / 32, VALUE_DIM_ / 32), tb32, 0, stream>>>(W_out, WoutT, VALUE_DIM_, D_);

  gemm128<<<dim3(CONV_DIM_ / 128, BT_ / 128), 256, 0, stream>>>(hidden_bf, WqkvT, mixed, BT_, CONV_DIM_, D_);
  gemm128<<<dim3(VALUE_DIM_ / 128, BT_ / 128), 256, 0, stream>>>(hidden_bf, WzT, zbuf, BT_, VALUE_DIM_, D_);
  small_proj<<<BT_, 256, 0, stream>>>(hidden, W_b, W_a, dt_bias, A_log, betab, gb);
  conv_silu<<<BT_ * CONV_DIM_ / 256, 256, 0, stream>>>(mixed, conv_w, qkv);
  qknorm<<<BT_ * HK_ * 2, 64, 0, stream>>>(qkv, qn, kn);
  scan_kernel<<<256, 256, 0, stream>>>(qn, kn, qkv, gb, betab, obuf);
  rms_gate<<<BT_ * HV_, 64, 0, stream>>>(obuf, zbuf, norm_w, obf);
  gemm128<<<dim3(D_ / 128, BT_ / 128), 256, 0, stream>>>(obf, WoutT, out, BT_, D_, VALUE_DIM_);
}

// Round 2
// 615.994 us; speedup vs baseline: 1.6141x; 1.6141x over previous
//
#include <hip/hip_runtime.h>
#include <hip/hip_bf16.h>

// Problem constants (GatedDeltaNet: B=2, T=1024, D=2048, HK=8, HV=16, DK=DV=128, KW=4)
#define B_ 2
#define T_ 1024
#define D_ 2048
#define HK_ 8
#define HV_ 16
#define DK_ 128
#define DV_ 128
#define KEY_DIM_ 1024
#define VALUE_DIM_ 2048
#define CONV_DIM_ 4096
#define BT_ 2048   // B*T

typedef __attribute__((ext_vector_type(8))) short short8;
typedef __attribute__((ext_vector_type(4))) float f32x4;

__device__ __forceinline__ short f2bf(float x) {
  __hip_bfloat16 h = __float2bfloat16(x);
  return *reinterpret_cast<short*>(&h);
}

// DPP-based add of lane (this ^ pattern) within a 16-lane row. VALU pipe, no LDS.
template <int CTRL>
__device__ __forceinline__ float dpp_add(float x) {
  int r = __builtin_amdgcn_update_dpp(0, __float_as_int(x), CTRL, 0xF, 0xF, true);
  return x + __int_as_float(r);
}
// full sum across 16-lane row, result in all 16 lanes:
__device__ __forceinline__ float row16_sum(float x) {
  x = dpp_add<0xB1>(x);    // quad_perm [1,0,3,2]  : xor 1
  x = dpp_add<0x4E>(x);    // quad_perm [2,3,0,1]  : xor 2
  x = dpp_add<0x124>(x);   // row_ror:4
  x = dpp_add<0x128>(x);   // row_ror:8
  return x;
}

// ---------------- cast f32 -> bf16 (vectorized) ----------------
__global__ void cast_plain(const float* __restrict__ in, short* __restrict__ out, int n4) {
  int i = blockIdx.x * blockDim.x + threadIdx.x;
  if (i < n4) {
    float4 v = ((const float4*)in)[i];
    short4 o;
    o.x = f2bf(v.x); o.y = f2bf(v.y); o.z = f2bf(v.z); o.w = f2bf(v.w);
    ((short4*)out)[i] = o;
  }
}

// ---------------- transpose + cast: W[R,C] f32 -> WT[C,R] bf16 ----------------
__global__ void transpose_cast(const float* __restrict__ W, short* __restrict__ WT, int R, int C) {
  __shared__ float tile[32][33];
  int tx = threadIdx.x, ty = threadIdx.y;
  int x = blockIdx.x * 32 + tx;
#pragma unroll
  for (int j = 0; j < 4; ++j) {
    int r = blockIdx.y * 32 + ty + j * 8;
    tile[ty + j * 8][tx] = W[(long)r * C + x];
  }
  __syncthreads();
  int ro = blockIdx.y * 32 + tx;
#pragma unroll
  for (int j = 0; j < 4; ++j) {
    int co = blockIdx.x * 32 + ty + j * 8;
    WT[(long)co * R + ro] = f2bf(tile[tx][ty + j * 8]);
  }
}

// ---------------- bf16 MFMA GEMM: C[M,N] f32 = A[M,K] * Bt[N,K]^T ----------------
__global__ __launch_bounds__(256) void gemm128(const short* __restrict__ A,
                                               const short* __restrict__ Bt,
                                               float* __restrict__ C,
                                               int M, int N, int K) {
  __shared__ short As[128][40];
  __shared__ short Bs[128][40];
  int m0 = blockIdx.y * 128, n0 = blockIdx.x * 128;
  int tid = threadIdx.x;
  int wave = tid >> 6, lane = tid & 63;
  int wm = (wave >> 1) * 64, wn = (wave & 1) * 64;
  int quad = lane >> 4, l16 = lane & 15;
  f32x4 acc[4][4] = {};

  int ar = tid >> 2;            // 0..63
  int ac = (tid & 3) * 8;       // 0,8,16,24
  const short* Ap0 = A + (long)(m0 + ar) * K + ac;
  const short* Ap1 = A + (long)(m0 + 64 + ar) * K + ac;
  const short* Bp0 = Bt + (long)(n0 + ar) * K + ac;
  const short* Bp1 = Bt + (long)(n0 + 64 + ar) * K + ac;

  for (int k0 = 0; k0 < K; k0 += 32) {
    short8 a0 = *(const short8*)(Ap0 + k0);
    short8 a1 = *(const short8*)(Ap1 + k0);
    short8 b0 = *(const short8*)(Bp0 + k0);
    short8 b1 = *(const short8*)(Bp1 + k0);
    __syncthreads();
    *(short8*)(&As[ar][ac]) = a0;
    *(short8*)(&As[64 + ar][ac]) = a1;
    *(short8*)(&Bs[ar][ac]) = b0;
    *(short8*)(&Bs[64 + ar][ac]) = b1;
    __syncthreads();

    short8 af[4], bf_[4];
#pragma unroll
    for (int i = 0; i < 4; ++i) af[i] = *(const short8*)(&As[wm + i * 16 + l16][quad * 8]);
#pragma unroll
    for (int j = 0; j < 4; ++j) bf_[j] = *(const short8*)(&Bs[wn + j * 16 + l16][quad * 8]);
#pragma unroll
    for (int i = 0; i < 4; ++i)
#pragma unroll
      for (int j = 0; j < 4; ++j)
        acc[i][j] = __builtin_amdgcn_mfma_f32_16x16x32_bf16(af[i], bf_[j], acc[i][j], 0, 0, 0);
  }

#pragma unroll
  for (int i = 0; i < 4; ++i)
#pragma unroll
    for (int j = 0; j < 4; ++j)
#pragma unroll
      for (int r = 0; r < 4; ++r) {
        int row = m0 + wm + i * 16 + quad * 4 + r;
        int colx = n0 + wn + j * 16 + l16;
        C[(long)row * N + colx] = acc[i][j][r];
      }
}

// ---------------- beta / exp(g) projections (fp32) ----------------
// betaT/egT stored transposed: [hv][b*t] so the scan's per-t uniform loads are
// sequential within one cache line.
__global__ __launch_bounds__(256) void small_proj(const float* __restrict__ hidden,
                                                  const float* __restrict__ Wb,
                                                  const float* __restrict__ Wa,
                                                  const float* __restrict__ dt_bias,
                                                  const float* __restrict__ A_log,
                                                  float* __restrict__ betaT,
                                                  float* __restrict__ egT) {
  __shared__ float red[256];
  int r = blockIdx.x;                     // row in [0, B*T)
  int tid = threadIdx.x;
  int h = tid & 31;                       // 0..15 -> W_b col, 16..31 -> W_a col
  int s = tid >> 5;                       // 0..7 K-slice
  const float* W = (h < 16) ? (Wb + h) : (Wa + (h - 16));
  const float* hp = hidden + (long)r * D_ + s * 256;
  float acc = 0.f;
#pragma unroll 8
  for (int i = 0; i < 256; ++i) acc += hp[i] * W[(s * 256 + i) * 16];
  red[tid] = acc;
  __syncthreads();
  if (tid < 32) {
    float t = 0.f;
#pragma unroll
    for (int ss = 0; ss < 8; ++ss) t += red[ss * 32 + tid];
    if (tid < 16) {
      betaT[tid * BT_ + r] = 1.f / (1.f + __expf(-t));
    } else {
      int hh = tid - 16;
      float y = t + dt_bias[hh];
      float sp = fmaxf(y, 0.f) + log1pf(__expf(-fabsf(y)));  // stable softplus
      egT[hh * BT_ + r] = __expf(-__expf(A_log[hh]) * sp);   // exp(g) precomputed
    }
  }
}

// ---------------- depthwise causal conv (K=4) + SiLU ----------------
__global__ void conv_silu(const float* __restrict__ x, const float* __restrict__ w,
                          float* __restrict__ y) {
  int idx = blockIdx.x * 256 + threadIdx.x;     // B*T*CONV_DIM
  int c = idx & (CONV_DIM_ - 1);
  int bt = idx >> 12;
  int t = bt & (T_ - 1);
  float4 wc = *(const float4*)(w + c * 4);
  const float* xp = x + (long)idx;
  float acc = wc.w * xp[0];
  if (t >= 1) acc += wc.z * xp[-CONV_DIM_];
  if (t >= 2) acc += wc.y * xp[-2 * CONV_DIM_];
  if (t >= 3) acc += wc.x * xp[-3 * CONV_DIM_];
  y[idx] = acc * (1.f / (1.f + __expf(-acc)));
}

// ---------------- q/k l2norm (+ q scale) ----------------
__global__ __launch_bounds__(64) void qknorm(const float* __restrict__ qkv,
                                             float* __restrict__ qn, float* __restrict__ kn) {
  int bi = blockIdx.x;          // B*T*HK*2
  int which = bi & 1;           // 0=q, 1=k
  int h = (bi >> 1) & 7;
  int bt = bi >> 4;
  int lane = threadIdx.x;
  const float* src = qkv + (long)bt * CONV_DIM_ + which * KEY_DIM_ + h * DK_;
  float2 v = *(const float2*)(src + lane * 2);
  float ss = v.x * v.x + v.y * v.y;
#pragma unroll
  for (int m = 32; m; m >>= 1) ss += __shfl_xor(ss, m, 64);
  float scale = rsqrtf(ss + 1e-6f);
  if (which == 0) scale *= 0.08838834764831845f;  // DK^-0.5
  float* dst = (which ? kn : qn) + ((long)bt * HK_ + h) * DK_;
  float2 o; o.x = v.x * scale; o.y = v.y * scale;
  ((float2*)dst)[lane] = o;
}

// ---------------- gated delta-rule scan ----------------
// grid: 256 blocks = (b, hv, oct) ; block: 256 threads = 16 cols x 16 k-groups.
// Each thread holds 8 state rows of one v-column in VGPRs. 4-deep register
// prefetch (load-to-use ~4 iters); 16-lane reductions via DPP (VALU pipe).
__global__ __launch_bounds__(256, 1) void scan_kernel(const float* __restrict__ qn,
                                                      const float* __restrict__ kn,
                                                      const float* __restrict__ qkv,
                                                      const float* __restrict__ egT,
                                                      const float* __restrict__ bT,
                                                      float* __restrict__ obuf) {
  int bi = blockIdx.x;
  int oct = bi & 7, hv = (bi >> 3) & 15, b = bi >> 7;
  int hk = hv >> 1;  // GQA repeat_interleave: expanded head j -> source j/2
  int tid = threadIdx.x;
  int kt = tid & 15, vg = tid >> 4;
  int col = oct * 16 + vg;

  const float* kp = kn + ((long)(b * T_) * HK_ + hk) * DK_ + kt * 8;
  const float* qp = qn + ((long)(b * T_) * HK_ + hk) * DK_ + kt * 8;
  const float* vp = qkv + (long)(b * T_) * CONV_DIM_ + 2 * KEY_DIM_ + hv * DV_ + col;
  const float* gp = egT + (hv * B_ + b) * T_;
  const float* bp = bT + (hv * B_ + b) * T_;
  float* op = obuf + ((long)(b * T_) * HV_ + hv) * DV_ + col;

  const int kstep = HK_ * DK_;    // 1024 floats per t
  const int vstep = CONV_DIM_;    // 4096

  float S[8] = {0, 0, 0, 0, 0, 0, 0, 0};

  // 4-deep rotating prefetch buffers
  float4 KA[4], KB[4], QA[4], QB[4];
  float V[4], G[4], Bt[4];
#pragma unroll
  for (int j = 0; j < 4; ++j) {
    KA[j] = *(const float4*)(kp + (long)j * kstep);
    KB[j] = *(const float4*)(kp + (long)j * kstep + 4);
    QA[j] = *(const float4*)(qp + (long)j * kstep);
    QB[j] = *(const float4*)(qp + (long)j * kstep + 4);
    V[j]  = vp[(long)j * vstep];
    G[j]  = gp[j];
    Bt[j] = bp[j];
  }

  for (int t = 0; t < T_; t += 4) {
#pragma unroll
    for (int j = 0; j < 4; ++j) {
      int tc = t + j;
      // consume buffer j
      float4 ka = KA[j], kb = KB[j], qa = QA[j], qb = QB[j];
      float vv = V[j], eg = G[j], bb = Bt[j];
      // refill buffer j for tc+4 (clamped; extra reload of 1023 is harmless)
      int tn = tc + 4; if (tn > T_ - 1) tn = T_ - 1;
      KA[j] = *(const float4*)(kp + (long)tn * kstep);
      KB[j] = *(const float4*)(kp + (long)tn * kstep + 4);
      QA[j] = *(const float4*)(qp + (long)tn * kstep);
      QB[j] = *(const float4*)(qp + (long)tn * kstep + 4);
      V[j]  = vp[(long)tn * vstep];
      G[j]  = gp[tn];
      Bt[j] = bp[tn];

      // k . S  (decay folded: k.(S*eg) = eg*(k.S))
      float p = ka.x * S[0] + ka.y * S[1] + ka.z * S[2] + ka.w * S[3]
              + kb.x * S[4] + kb.y * S[5] + kb.z * S[6] + kb.w * S[7];
      p = row16_sum(p);
      float vadj = (vv - eg * p) * bb;
      S[0] = S[0] * eg + ka.x * vadj;
      S[1] = S[1] * eg + ka.y * vadj;
      S[2] = S[2] * eg + ka.z * vadj;
      S[3] = S[3] * eg + ka.w * vadj;
      S[4] = S[4] * eg + kb.x * vadj;
      S[5] = S[5] * eg + kb.y * vadj;
      S[6] = S[6] * eg + kb.z * vadj;
      S[7] = S[7] * eg + kb.w * vadj;
      float o = qa.x * S[0] + qa.y * S[1] + qa.z * S[2] + qa.w * S[3]
              + qb.x * S[4] + qb.y * S[5] + qb.z * S[6] + qb.w * S[7];
      o = row16_sum(o);          // off the recurrence critical path
      if (kt == 0) op[(long)tc * VALUE_DIM_] = o;
    }
  }
}

// ---------------- gated RMSNorm * silu(z), cast to bf16 ----------------
__global__ __launch_bounds__(64) void rms_gate(const float* __restrict__ obuf,
                                               const float* __restrict__ zbuf,
                                               const float* __restrict__ nw,
                                               short* __restrict__ obf) {
  int bi = blockIdx.x;          // B*T*HV
  int hv = bi & 15;
  int bt = bi >> 4;
  int lane = threadIdx.x;
  const float* o = obuf + ((long)bt * HV_ + hv) * DV_;
  float2 ov = *(const float2*)(o + lane * 2);
  float ss = ov.x * ov.x + ov.y * ov.y;
#pragma unroll
  for (int m = 32; m; m >>= 1) ss += __shfl_xor(ss, m, 64);
  float scale = rsqrtf(ss * (1.f / 128.f) + 1e-6f);
  float2 wv = *(const float2*)(nw + lane * 2);
  const float* z = zbuf + (long)bt * VALUE_DIM_ + hv * DV_;
  float2 zv = *(const float2*)(z + lane * 2);
  float s0 = zv.x * (1.f / (1.f + __expf(-zv.x)));
  float s1 = zv.y * (1.f / (1.f + __expf(-zv.y)));
  short2 r;
  r.x = f2bf(ov.x * scale * wv.x * s0);
  r.y = f2bf(ov.y * scale * wv.y * s1);
  ((short2*)(obf + ((long)bt * VALUE_DIM_ + hv * DV_)))[lane] = r;
}

// ---------------- launcher ----------------
extern "C" void kernel_launch(void* const* d_in, const int* in_sizes, int n_in,
                              void* d_out, int out_size, void* d_ws, size_t ws_size,
                              hipStream_t stream) {
  const float* hidden  = (const float*)d_in[0];
  const float* W_qkv   = (const float*)d_in[1];
  const float* W_z     = (const float*)d_in[2];
  const float* W_b     = (const float*)d_in[3];
  const float* W_a     = (const float*)d_in[4];
  const float* conv_w  = (const float*)d_in[5];
  const float* dt_bias = (const float*)d_in[6];
  const float* A_log   = (const float*)d_in[7];
  const float* norm_w  = (const float*)d_in[8];
  const float* W_out   = (const float*)d_in[9];
  float* out = (float*)d_out;

  char* ws = (char*)d_ws;
  size_t off = 0;
  auto alloc = [&](size_t bytes) {
    void* p = ws + off;
    off += (bytes + 255) & ~(size_t)255;
    return p;
  };
  short* hidden_bf = (short*)alloc((size_t)BT_ * D_ * 2);          // 8 MB
  short* WqkvT     = (short*)alloc((size_t)CONV_DIM_ * D_ * 2);    // 16 MB
  short* WzT       = (short*)alloc((size_t)VALUE_DIM_ * D_ * 2);   // 8 MB
  short* WoutT     = (short*)alloc((size_t)D_ * VALUE_DIM_ * 2);   // 8 MB
  float* mixed     = (float*)alloc((size_t)BT_ * CONV_DIM_ * 4);   // 32 MB
  float* qkv       = (float*)alloc((size_t)BT_ * CONV_DIM_ * 4);   // 32 MB
  float* zbuf      = (float*)alloc((size_t)BT_ * VALUE_DIM_ * 4);  // 16 MB
  float* qn        = (float*)alloc((size_t)BT_ * KEY_DIM_ * 4);    // 8 MB
  float* kn        = (float*)alloc((size_t)BT_ * KEY_DIM_ * 4);    // 8 MB
  float* betab     = (float*)alloc((size_t)BT_ * HV_ * 4);
  float* gb        = (float*)alloc((size_t)BT_ * HV_ * 4);
  float* obuf = mixed;       // alias: mixed dead after conv_silu
  short* obf  = hidden_bf;   // alias: hidden_bf dead after gemm(z)

  dim3 tb32(32, 8);
  cast_plain<<<(BT_ * D_ / 4 + 255) / 256, 256, 0, stream>>>(hidden, hidden_bf, BT_ * D_ / 4);
  transpose_cast<<<dim3(CONV_DIM_ / 32, D_ / 32), tb32, 0, stream>>>(W_qkv, WqkvT, D_, CONV_DIM_);
  transpose_cast<<<dim3(VALUE_DIM_ / 32, D_ / 32), tb32, 0, stream>>>(W_z, WzT, D_, VALUE_DIM_);
  transpose_cast<<<dim3(D_ / 32, VALUE_DIM_ / 32), tb32, 0, stream>>>(W_out, WoutT, VALUE_DIM_, D_);

  gemm128<<<dim3(CONV_DIM_ / 128, BT_ / 128), 256, 0, stream>>>(hidden_bf, WqkvT, mixed, BT_, CONV_DIM_, D_);
  gemm128<<<dim3(VALUE_DIM_ / 128, BT_ / 128), 256, 0, stream>>>(hidden_bf, WzT, zbuf, BT_, VALUE_DIM_, D_);
  small_proj<<<BT_, 256, 0, stream>>>(hidden, W_b, W_a, dt_bias, A_log, betab, gb);
  conv_silu<<<BT_ * CONV_DIM_ / 256, 256, 0, stream>>>(mixed, conv_w, qkv);
  qknorm<<<BT_ * HK_ * 2, 64, 0, stream>>>(qkv, qn, kn);
  scan_kernel<<<256, 256, 0, stream>>>(qn, kn, qkv, gb, betab, obuf);
  rms_gate<<<BT_ * HV_, 64, 0, stream>>>(obuf, zbuf, norm_w, obf);
  gemm128<<<dim3(D_ / 128, BT_ / 128), 256, 0, stream>>>(obf, WoutT, out, BT_, D_, VALUE_DIM_);
}